// Round 1
// baseline (330.107 us; speedup 1.0000x reference)
//
#include <hip/hip_runtime.h>

// ---------------- problem constants ----------------
// B=4096 batch, D=2048 dim, H=3 hidden layers, O=1 output
#define BB 4096
#define DD 2048

typedef float f32x4 __attribute__((ext_vector_type(4)));
typedef __bf16 bf16x8 __attribute__((ext_vector_type(8)));

typedef __attribute__((address_space(1))) unsigned int gl_u32;
typedef __attribute__((address_space(3))) unsigned int lds_u32;

#define GLOAD_LDS16(gptr, sptr) \
  __builtin_amdgcn_global_load_lds((gl_u32*)(void*)(gptr), (lds_u32*)(sptr), 16, 0, 0)

__device__ __forceinline__ unsigned short f2bf(float f) {
  unsigned int u = __float_as_uint(f);
  u += 0x7fffu + ((u >> 16) & 1u);   // round-to-nearest-even
  return (unsigned short)(u >> 16);
}

__device__ __forceinline__ float sp(float x) {  // softplus, stable
  return fmaxf(x, 0.0f) + log1pf(__expf(-fabsf(x)));
}

// ---------------- prep: materialize weights (bf16), biases (f32), x->bf16 ----
// vec4 regions: [W_h | x | b_h | w_o | b_o]
__global__ void prep_kernel(
    const float* __restrict__ x,
    const float* __restrict__ wmuh, const float* __restrict__ wrhoh,
    const float* __restrict__ bmuh, const float* __restrict__ brhoh,
    const float* __restrict__ wmuo, const float* __restrict__ wrhoo,
    const float* __restrict__ bmuo, const float* __restrict__ brhoo,
    const float* __restrict__ epswh, const float* __restrict__ epsbh,
    const float* __restrict__ epswo, const float* __restrict__ epsbo,
    unsigned short* __restrict__ Wh, unsigned short* __restrict__ Xb,
    float* __restrict__ bh, float* __restrict__ wo, float* __restrict__ bo)
{
  const long long RW = 3LL * DD * DD / 4;   // 3,145,728
  const long long RX = (long long)BB * DD / 4; // 2,097,152
  const long long RBH = 3LL * DD / 4;       // 1536
  const long long RO = DD / 4;              // 512
  long long i = (long long)blockIdx.x * 256 + threadIdx.x;
  if (i < RW) {
    float4 m = ((const float4*)wmuh)[i];
    float4 r = ((const float4*)wrhoh)[i];
    float4 e = ((const float4*)epswh)[i];
    ushort4 o;
    o.x = f2bf(m.x + e.x * sp(r.x));
    o.y = f2bf(m.y + e.y * sp(r.y));
    o.z = f2bf(m.z + e.z * sp(r.z));
    o.w = f2bf(m.w + e.w * sp(r.w));
    ((ushort4*)Wh)[i] = o;
    return;
  }
  i -= RW;
  if (i < RX) {
    float4 v = ((const float4*)x)[i];
    ushort4 o;
    o.x = f2bf(v.x); o.y = f2bf(v.y); o.z = f2bf(v.z); o.w = f2bf(v.w);
    ((ushort4*)Xb)[i] = o;
    return;
  }
  i -= RX;
  if (i < RBH) {
    float4 m = ((const float4*)bmuh)[i];
    float4 r = ((const float4*)brhoh)[i];
    float4 e = ((const float4*)epsbh)[i];
    float4 o;
    o.x = m.x + e.x * sp(r.x);
    o.y = m.y + e.y * sp(r.y);
    o.z = m.z + e.z * sp(r.z);
    o.w = m.w + e.w * sp(r.w);
    ((float4*)bh)[i] = o;
    return;
  }
  i -= RBH;
  if (i < RO) {
    float4 m = ((const float4*)wmuo)[i];
    float4 r = ((const float4*)wrhoo)[i];
    float4 e = ((const float4*)epswo)[i];
    float4 o;
    o.x = m.x + e.x * sp(r.x);
    o.y = m.y + e.y * sp(r.y);
    o.z = m.z + e.z * sp(r.z);
    o.w = m.w + e.w * sp(r.w);
    ((float4*)wo)[i] = o;
    return;
  }
  i -= RO;
  if (i == 0) {
    bo[0] = bmuo[0] + epsbo[0] * sp(brhoo[0]);
  }
}

// ---------------- GEMM: C = relu(A @ W^T + bias), all bf16 in / bf16 out ----
// A: MxK row-major bf16, W: NxK row-major bf16 (K-contiguous both => gemm_bt)
// 128x128 block tile, BK=64, 256 threads = 4 waves (2x2), each wave 64x64
// via 4x4 grid of 16x16x32 MFMA tiles. global_load_lds(16B) staging with
// XOR swizzle folded into the *global* address (keeps wave-uniform LDS dest).
__global__ __launch_bounds__(256) void gemm_relu_kernel(
    const unsigned short* __restrict__ A,
    const unsigned short* __restrict__ W,
    const float* __restrict__ bias,
    unsigned short* __restrict__ C,
    int N, int K)
{
  __shared__ unsigned short sA[128 * 64];
  __shared__ unsigned short sB[128 * 64];

  const int t = threadIdx.x;
  const int w = t >> 6;
  const int l = t & 63;
  const int lq = l >> 4;     // quad 0..3
  const int lr = l & 15;     // lane-in-quad 0..15
  const int m0 = blockIdx.y * 128;
  const int n0 = blockIdx.x * 128;
  const int mw = (w >> 1) * 64;   // wave row offset in tile
  const int nw = (w & 1) * 64;    // wave col offset in tile

  f32x4 acc[4][4] = {};

  // staging geometry (kt-independent): chunk c = i*256 + t, 16B per chunk
  int srow[4], sgc[4];
  #pragma unroll
  for (int i = 0; i < 4; ++i) {
    int c = i * 256 + t;
    srow[i] = c >> 3;                    // tile row 0..127
    sgc[i] = (c & 7) ^ (srow[i] & 7);    // swizzled global 16B-chunk col 0..7
  }

  for (int kt = 0; kt < K; kt += 64) {
    #pragma unroll
    for (int i = 0; i < 4; ++i) {
      int c = i * 256 + t;
      const unsigned short* ga = A + (size_t)(m0 + srow[i]) * K + kt + sgc[i] * 8;
      GLOAD_LDS16(ga, &sA[c * 8]);
      const unsigned short* gb = W + (size_t)(n0 + srow[i]) * K + kt + sgc[i] * 8;
      GLOAD_LDS16(gb, &sB[c * 8]);
    }
    __syncthreads();   // drains vmcnt (global_load_lds) before use

    #pragma unroll
    for (int s = 0; s < 2; ++s) {       // two K=32 sub-steps
      bf16x8 af[4], bfr[4];
      #pragma unroll
      for (int i = 0; i < 4; ++i) {
        int ra = mw + i * 16 + lr;
        int g = s * 4 + lq;
        af[i] = *(const bf16x8*)&sA[ra * 64 + (g ^ (ra & 7)) * 8];
        int rb = nw + i * 16 + lr;
        bfr[i] = *(const bf16x8*)&sB[rb * 64 + (g ^ (rb & 7)) * 8];
      }
      #pragma unroll
      for (int i = 0; i < 4; ++i)
        #pragma unroll
        for (int j = 0; j < 4; ++j)
          acc[i][j] = __builtin_amdgcn_mfma_f32_16x16x32_bf16(af[i], bfr[j], acc[i][j], 0, 0, 0);
    }
    __syncthreads();   // protect LDS from next iteration's staging
  }

  // epilogue: C[m][n], m = base + quad*4 + r, n = base + lr  (m89-verified map)
  #pragma unroll
  for (int j = 0; j < 4; ++j) {
    int n = n0 + nw + j * 16 + lr;
    float bv = bias[n];
    #pragma unroll
    for (int i = 0; i < 4; ++i) {
      int mbase = m0 + mw + i * 16 + lq * 4;
      #pragma unroll
      for (int r = 0; r < 4; ++r) {
        float v = acc[i][j][r] + bv;
        v = fmaxf(v, 0.0f);
        C[(size_t)(mbase + r) * N + n] = f2bf(v);
      }
    }
  }
}

// ---------------- final: out[m] = h2[m,:] . wo + bo  (one wave per row) ----
__global__ void final_kernel(const unsigned short* __restrict__ H,
                             const float* __restrict__ wo,
                             const float* __restrict__ bo,
                             float* __restrict__ out)
{
  const int row = blockIdx.x * 4 + (threadIdx.x >> 6);
  const int l = threadIdx.x & 63;
  const unsigned short* hr = H + (size_t)row * DD;
  float sum = 0.0f;
  #pragma unroll
  for (int s = 0; s < 4; ++s) {
    int k = s * 512 + l * 8;
    uint4 hv = *(const uint4*)&hr[k];
    float4 w0 = *(const float4*)&wo[k];
    float4 w1 = *(const float4*)&wo[k + 4];
    sum += __uint_as_float(hv.x << 16) * w0.x;
    sum += __uint_as_float(hv.x & 0xffff0000u) * w0.y;
    sum += __uint_as_float(hv.y << 16) * w0.z;
    sum += __uint_as_float(hv.y & 0xffff0000u) * w0.w;
    sum += __uint_as_float(hv.z << 16) * w1.x;
    sum += __uint_as_float(hv.z & 0xffff0000u) * w1.y;
    sum += __uint_as_float(hv.w << 16) * w1.z;
    sum += __uint_as_float(hv.w & 0xffff0000u) * w1.w;
  }
  #pragma unroll
  for (int off = 32; off > 0; off >>= 1)
    sum += __shfl_down(sum, off, 64);
  if (l == 0) out[row] = sum + bo[0];
}

// ---------------- launch ----------------
extern "C" void kernel_launch(void* const* d_in, const int* in_sizes, int n_in,
                              void* d_out, int out_size, void* d_ws, size_t ws_size,
                              hipStream_t stream) {
  const float* x     = (const float*)d_in[0];
  const float* wmuh  = (const float*)d_in[1];
  const float* wrhoh = (const float*)d_in[2];
  const float* bmuh  = (const float*)d_in[3];
  const float* brhoh = (const float*)d_in[4];
  const float* wmuo  = (const float*)d_in[5];
  const float* wrhoo = (const float*)d_in[6];
  const float* bmuo  = (const float*)d_in[7];
  const float* brhoo = (const float*)d_in[8];
  const float* epswh = (const float*)d_in[9];
  const float* epsbh = (const float*)d_in[10];
  const float* epswo = (const float*)d_in[11];
  const float* epsbo = (const float*)d_in[12];

  char* ws = (char*)d_ws;
  // layout (bytes):
  unsigned short* Wh = (unsigned short*)(ws);                    // 3*2048*2048*2 = 25165824
  unsigned short* Xb = (unsigned short*)(ws + 25165824);         // 4096*2048*2  = 16777216
  unsigned short* Ha = (unsigned short*)(ws + 25165824 + 16777216);
  unsigned short* Hb = (unsigned short*)(ws + 25165824 + 2 * 16777216);
  float* bh = (float*)(ws + 25165824 + 3 * 16777216);            // 3*2048*4 = 24576
  float* wo = (float*)(ws + 25165824 + 3 * 16777216 + 24576);    // 2048*4   = 8192
  float* bo = (float*)(ws + 25165824 + 3 * 16777216 + 24576 + 8192);

  // prep: total vec4 work items = 3145728 + 2097152 + 1536 + 512 + 1 = 5244929
  const int prep_blocks = (5244929 + 255) / 256;  // 20489
  prep_kernel<<<prep_blocks, 256, 0, stream>>>(
      x, wmuh, wrhoh, bmuh, brhoh, wmuo, wrhoo, bmuo, brhoo,
      epswh, epsbh, epswo, epsbo, Wh, Xb, bh, wo, bo);

  dim3 ggrid(DD / 128, BB / 128);  // (16, 32)
  gemm_relu_kernel<<<ggrid, 256, 0, stream>>>(Xb, Wh,                 bh,            Ha, DD, DD);
  gemm_relu_kernel<<<ggrid, 256, 0, stream>>>(Ha, Wh + 1 * 4194304,   bh + DD,       Hb, DD, DD);
  gemm_relu_kernel<<<ggrid, 256, 0, stream>>>(Hb, Wh + 2 * 4194304,   bh + 2 * DD,   Xb, DD, DD);  // h2 -> reuse Xb

  final_kernel<<<BB / 4, 256, 0, stream>>>(Xb, wo, bo, (float*)d_out);
}

// Round 2
// 327.207 us; speedup vs baseline: 1.0089x; 1.0089x over previous
//
#include <hip/hip_runtime.h>

// ---------------- problem constants ----------------
// B=4096 batch, D=2048 dim, H=3 hidden layers, O=1 output
#define BB 4096
#define DD 2048

typedef float f32x4 __attribute__((ext_vector_type(4)));
typedef __bf16 bf16x8 __attribute__((ext_vector_type(8)));

typedef __attribute__((address_space(1))) unsigned int gl_u32;
typedef __attribute__((address_space(3))) unsigned int lds_u32;

#define GLOAD_LDS16(gptr, sptr) \
  __builtin_amdgcn_global_load_lds((gl_u32*)(void*)(gptr), (lds_u32*)(sptr), 16, 0, 0)

__device__ __forceinline__ unsigned short f2bf(float f) {
  unsigned int u = __float_as_uint(f);
  u += 0x7fffu + ((u >> 16) & 1u);   // round-to-nearest-even
  return (unsigned short)(u >> 16);
}

// fast softplus: v_exp_f32 + v_log_f32 (quarter-rate HW ops).
// abs err ~6e-8 — negligible vs bf16 quantization of the weight.
__device__ __forceinline__ float sp(float x) {
  float t = __expf(-fabsf(x));
  return fmaxf(x, 0.0f) + __logf(1.0f + t);
}

// ---------------- prep: materialize weights (bf16), biases (f32), x->bf16 ----
// vec4 regions: [W_h | x | b_h | w_o | b_o]
__global__ void prep_kernel(
    const float* __restrict__ x,
    const float* __restrict__ wmuh, const float* __restrict__ wrhoh,
    const float* __restrict__ bmuh, const float* __restrict__ brhoh,
    const float* __restrict__ wmuo, const float* __restrict__ wrhoo,
    const float* __restrict__ bmuo, const float* __restrict__ brhoo,
    const float* __restrict__ epswh, const float* __restrict__ epsbh,
    const float* __restrict__ epswo, const float* __restrict__ epsbo,
    unsigned short* __restrict__ Wh, unsigned short* __restrict__ Xb,
    float* __restrict__ bh, float* __restrict__ wo, float* __restrict__ bo)
{
  const long long RW = 3LL * DD * DD / 4;   // 3,145,728
  const long long RX = (long long)BB * DD / 4; // 2,097,152
  const long long RBH = 3LL * DD / 4;       // 1536
  const long long RO = DD / 4;              // 512
  long long i = (long long)blockIdx.x * 256 + threadIdx.x;
  if (i < RW) {
    float4 m = ((const float4*)wmuh)[i];
    float4 r = ((const float4*)wrhoh)[i];
    float4 e = ((const float4*)epswh)[i];
    ushort4 o;
    o.x = f2bf(m.x + e.x * sp(r.x));
    o.y = f2bf(m.y + e.y * sp(r.y));
    o.z = f2bf(m.z + e.z * sp(r.z));
    o.w = f2bf(m.w + e.w * sp(r.w));
    ((ushort4*)Wh)[i] = o;
    return;
  }
  i -= RW;
  if (i < RX) {
    float4 v = ((const float4*)x)[i];
    ushort4 o;
    o.x = f2bf(v.x); o.y = f2bf(v.y); o.z = f2bf(v.z); o.w = f2bf(v.w);
    ((ushort4*)Xb)[i] = o;
    return;
  }
  i -= RX;
  if (i < RBH) {
    float4 m = ((const float4*)bmuh)[i];
    float4 r = ((const float4*)brhoh)[i];
    float4 e = ((const float4*)epsbh)[i];
    float4 o;
    o.x = m.x + e.x * sp(r.x);
    o.y = m.y + e.y * sp(r.y);
    o.z = m.z + e.z * sp(r.z);
    o.w = m.w + e.w * sp(r.w);
    ((float4*)bh)[i] = o;
    return;
  }
  i -= RBH;
  if (i < RO) {
    float4 m = ((const float4*)wmuo)[i];
    float4 r = ((const float4*)wrhoo)[i];
    float4 e = ((const float4*)epswo)[i];
    float4 o;
    o.x = m.x + e.x * sp(r.x);
    o.y = m.y + e.y * sp(r.y);
    o.z = m.z + e.z * sp(r.z);
    o.w = m.w + e.w * sp(r.w);
    ((float4*)wo)[i] = o;
    return;
  }
  i -= RO;
  if (i == 0) {
    bo[0] = bmuo[0] + epsbo[0] * sp(brhoo[0]);
  }
}

// ---------------- GEMM: C = relu(A @ W^T + bias), all bf16 in / bf16 out ----
// A: MxK row-major bf16 (M=4096), W: NxK row-major bf16 (N=2048), K=2048.
// 128x128 block tile, BK=64, 256 threads = 4 waves (2x2), each wave 64x64
// via 4x4 grid of 16x16x32 MFMA tiles. global_load_lds(16B) staging with
// XOR swizzle folded into the *global* address (keeps wave-uniform LDS dest).
// 1D grid of 512 blocks; XCD-aware remap: each XCD's 64 co-resident blocks
// (dispatch round-robin id%8) cover an 8x8 tile patch -> per-XCD L2
// footprint = 4MB (B) + 4MB (A), B patch fits the 4MB per-XCD L2.
__global__ __launch_bounds__(256) void gemm_relu_kernel(
    const unsigned short* __restrict__ A,
    const unsigned short* __restrict__ W,
    const float* __restrict__ bias,
    unsigned short* __restrict__ C,
    int N, int K)
{
  __shared__ unsigned short sA[128 * 64];
  __shared__ unsigned short sB[128 * 64];

  const int t = threadIdx.x;
  const int w = t >> 6;
  const int l = t & 63;
  const int lq = l >> 4;     // quad 0..3
  const int lr = l & 15;     // lane-in-quad 0..15

  // XCD-aware swizzle over 32 (M) x 16 (N) tiles
  const int id = blockIdx.x;
  const int p = id & 7;          // patch index == XCD (dispatch heuristic)
  const int i4 = id >> 3;        // 0..63 within patch
  const int mt = (p & 3) * 8 + (i4 & 7);   // 0..31
  const int nt = (p >> 2) * 8 + (i4 >> 3); // 0..15
  const int m0 = mt * 128;
  const int n0 = nt * 128;

  const int mw = (w >> 1) * 64;   // wave row offset in tile
  const int nw = (w & 1) * 64;    // wave col offset in tile

  f32x4 acc[4][4] = {};

  // staging geometry (kt-independent): chunk c = i*256 + t, 16B per chunk
  int srow[4], sgc[4];
  #pragma unroll
  for (int i = 0; i < 4; ++i) {
    int c = i * 256 + t;
    srow[i] = c >> 3;                    // tile row 0..127
    sgc[i] = (c & 7) ^ (srow[i] & 7);    // swizzled global 16B-chunk col 0..7
  }

  for (int kt = 0; kt < K; kt += 64) {
    #pragma unroll
    for (int i = 0; i < 4; ++i) {
      int c = i * 256 + t;
      const unsigned short* ga = A + (size_t)(m0 + srow[i]) * K + kt + sgc[i] * 8;
      GLOAD_LDS16(ga, &sA[c * 8]);
      const unsigned short* gb = W + (size_t)(n0 + srow[i]) * K + kt + sgc[i] * 8;
      GLOAD_LDS16(gb, &sB[c * 8]);
    }
    __syncthreads();   // drains vmcnt (global_load_lds) before use

    #pragma unroll
    for (int s = 0; s < 2; ++s) {       // two K=32 sub-steps
      bf16x8 af[4], bfr[4];
      #pragma unroll
      for (int i = 0; i < 4; ++i) {
        int ra = mw + i * 16 + lr;
        int g = s * 4 + lq;
        af[i] = *(const bf16x8*)&sA[ra * 64 + (g ^ (ra & 7)) * 8];
        int rb = nw + i * 16 + lr;
        bfr[i] = *(const bf16x8*)&sB[rb * 64 + (g ^ (rb & 7)) * 8];
      }
      #pragma unroll
      for (int i = 0; i < 4; ++i)
        #pragma unroll
        for (int j = 0; j < 4; ++j)
          acc[i][j] = __builtin_amdgcn_mfma_f32_16x16x32_bf16(af[i], bfr[j], acc[i][j], 0, 0, 0);
    }
    __syncthreads();   // protect LDS from next iteration's staging
  }

  // epilogue: C[m][n], m = base + quad*4 + r, n = base + lr  (m89-verified map)
  #pragma unroll
  for (int j = 0; j < 4; ++j) {
    int n = n0 + nw + j * 16 + lr;
    float bv = bias[n];
    #pragma unroll
    for (int i = 0; i < 4; ++i) {
      int mbase = m0 + mw + i * 16 + lq * 4;
      #pragma unroll
      for (int r = 0; r < 4; ++r) {
        float v = acc[i][j][r] + bv;
        v = fmaxf(v, 0.0f);
        C[(size_t)(mbase + r) * N + n] = f2bf(v);
      }
    }
  }
}

// ---------------- final: out[m] = h2[m,:] . wo + bo  (one wave per row) ----
__global__ void final_kernel(const unsigned short* __restrict__ H,
                             const float* __restrict__ wo,
                             const float* __restrict__ bo,
                             float* __restrict__ out)
{
  const int row = blockIdx.x * 4 + (threadIdx.x >> 6);
  const int l = threadIdx.x & 63;
  const unsigned short* hr = H + (size_t)row * DD;
  float sum = 0.0f;
  #pragma unroll
  for (int s = 0; s < 4; ++s) {
    int k = s * 512 + l * 8;
    uint4 hv = *(const uint4*)&hr[k];
    float4 w0 = *(const float4*)&wo[k];
    float4 w1 = *(const float4*)&wo[k + 4];
    sum += __uint_as_float(hv.x << 16) * w0.x;
    sum += __uint_as_float(hv.x & 0xffff0000u) * w0.y;
    sum += __uint_as_float(hv.y << 16) * w0.z;
    sum += __uint_as_float(hv.y & 0xffff0000u) * w0.w;
    sum += __uint_as_float(hv.z << 16) * w1.x;
    sum += __uint_as_float(hv.z & 0xffff0000u) * w1.y;
    sum += __uint_as_float(hv.w << 16) * w1.z;
    sum += __uint_as_float(hv.w & 0xffff0000u) * w1.w;
  }
  #pragma unroll
  for (int off = 32; off > 0; off >>= 1)
    sum += __shfl_down(sum, off, 64);
  if (l == 0) out[row] = sum + bo[0];
}

// ---------------- launch ----------------
extern "C" void kernel_launch(void* const* d_in, const int* in_sizes, int n_in,
                              void* d_out, int out_size, void* d_ws, size_t ws_size,
                              hipStream_t stream) {
  const float* x     = (const float*)d_in[0];
  const float* wmuh  = (const float*)d_in[1];
  const float* wrhoh = (const float*)d_in[2];
  const float* bmuh  = (const float*)d_in[3];
  const float* brhoh = (const float*)d_in[4];
  const float* wmuo  = (const float*)d_in[5];
  const float* wrhoo = (const float*)d_in[6];
  const float* bmuo  = (const float*)d_in[7];
  const float* brhoo = (const float*)d_in[8];
  const float* epswh = (const float*)d_in[9];
  const float* epsbh = (const float*)d_in[10];
  const float* epswo = (const float*)d_in[11];
  const float* epsbo = (const float*)d_in[12];

  char* ws = (char*)d_ws;
  // layout (bytes):
  unsigned short* Wh = (unsigned short*)(ws);                    // 3*2048*2048*2 = 25165824
  unsigned short* Xb = (unsigned short*)(ws + 25165824);         // 4096*2048*2  = 16777216
  unsigned short* Ha = (unsigned short*)(ws + 25165824 + 16777216);
  unsigned short* Hb = (unsigned short*)(ws + 25165824 + 2 * 16777216);
  float* bh = (float*)(ws + 25165824 + 3 * 16777216);            // 3*2048*4 = 24576
  float* wo = (float*)(ws + 25165824 + 3 * 16777216 + 24576);    // 2048*4   = 8192
  float* bo = (float*)(ws + 25165824 + 3 * 16777216 + 24576 + 8192);

  // prep: total vec4 work items = 3145728 + 2097152 + 1536 + 512 + 1 = 5244929
  const int prep_blocks = (5244929 + 255) / 256;  // 20489
  prep_kernel<<<prep_blocks, 256, 0, stream>>>(
      x, wmuh, wrhoh, bmuh, brhoh, wmuo, wrhoo, bmuo, brhoo,
      epswh, epsbh, epswo, epsbo, Wh, Xb, bh, wo, bo);

  const int ggrid = (BB / 128) * (DD / 128);  // 512 blocks, 1D with XCD swizzle
  gemm_relu_kernel<<<ggrid, 256, 0, stream>>>(Xb, Wh,                 bh,            Ha, DD, DD);
  gemm_relu_kernel<<<ggrid, 256, 0, stream>>>(Ha, Wh + 1 * 4194304,   bh + DD,       Hb, DD, DD);
  gemm_relu_kernel<<<ggrid, 256, 0, stream>>>(Hb, Wh + 2 * 4194304,   bh + 2 * DD,   Xb, DD, DD);  // h2 -> reuse Xb

  final_kernel<<<BB / 4, 256, 0, stream>>>(Xb, wo, bo, (float*)d_out);
}

// Round 3
// 315.904 us; speedup vs baseline: 1.0450x; 1.0358x over previous
//
#include <hip/hip_runtime.h>

// ---------------- problem constants ----------------
// B=4096 batch, D=2048 dim, H=3 hidden layers, O=1 output
#define BB 4096
#define DD 2048

typedef float f32x4 __attribute__((ext_vector_type(4)));
typedef __bf16 bf16x8 __attribute__((ext_vector_type(8)));

typedef __attribute__((address_space(1))) unsigned int gl_u32;
typedef __attribute__((address_space(3))) unsigned int lds_u32;

#define GLOAD_LDS16(gptr, sptr) \
  __builtin_amdgcn_global_load_lds((gl_u32*)(void*)(gptr), (lds_u32*)(sptr), 16, 0, 0)

__device__ __forceinline__ unsigned short f2bf(float f) {
  unsigned int u = __float_as_uint(f);
  u += 0x7fffu + ((u >> 16) & 1u);   // round-to-nearest-even
  return (unsigned short)(u >> 16);
}

// fast softplus: v_exp_f32 + v_log_f32 (quarter-rate HW ops).
__device__ __forceinline__ float sp(float x) {
  float t = __expf(-fabsf(x));
  return fmaxf(x, 0.0f) + __logf(1.0f + t);
}

// ---------------- prep: materialize weights (bf16), biases (f32), x->bf16 ----
// Latency-bound fix (R2): 4 independent vec4 items per thread, loads clustered
// -> 12 outstanding 16B loads per lane (vs 3), 4x fewer workgroups.
// Block regions: [0,3072) -> W_h (3,145,728 vec4, 1024/block)
//                [3072,5120) -> x (2,097,152 vec4, 1024/block)
//                [5120,5129) -> b_h (1536) | w_o (512) | b_o (1)
__global__ void prep_kernel(
    const float* __restrict__ x,
    const float* __restrict__ wmuh, const float* __restrict__ wrhoh,
    const float* __restrict__ bmuh, const float* __restrict__ brhoh,
    const float* __restrict__ wmuo, const float* __restrict__ wrhoo,
    const float* __restrict__ bmuo, const float* __restrict__ brhoo,
    const float* __restrict__ epswh, const float* __restrict__ epsbh,
    const float* __restrict__ epswo, const float* __restrict__ epsbo,
    unsigned short* __restrict__ Wh, unsigned short* __restrict__ Xb,
    float* __restrict__ bh, float* __restrict__ wo, float* __restrict__ bo)
{
  const int b = blockIdx.x;
  const int t = threadIdx.x;
  if (b < 3072) {
    long long base = (long long)b * 1024 + t;
    float4 m[4], r[4], e[4];
    #pragma unroll
    for (int j = 0; j < 4; ++j) {
      m[j] = ((const float4*)wmuh)[base + j * 256];
      r[j] = ((const float4*)wrhoh)[base + j * 256];
      e[j] = ((const float4*)epswh)[base + j * 256];
    }
    #pragma unroll
    for (int j = 0; j < 4; ++j) {
      ushort4 o;
      o.x = f2bf(m[j].x + e[j].x * sp(r[j].x));
      o.y = f2bf(m[j].y + e[j].y * sp(r[j].y));
      o.z = f2bf(m[j].z + e[j].z * sp(r[j].z));
      o.w = f2bf(m[j].w + e[j].w * sp(r[j].w));
      ((ushort4*)Wh)[base + j * 256] = o;
    }
    return;
  }
  if (b < 5120) {
    long long base = (long long)(b - 3072) * 1024 + t;
    float4 v[4];
    #pragma unroll
    for (int j = 0; j < 4; ++j) v[j] = ((const float4*)x)[base + j * 256];
    #pragma unroll
    for (int j = 0; j < 4; ++j) {
      ushort4 o;
      o.x = f2bf(v[j].x); o.y = f2bf(v[j].y); o.z = f2bf(v[j].z); o.w = f2bf(v[j].w);
      ((ushort4*)Xb)[base + j * 256] = o;
    }
    return;
  }
  long long i = (long long)(b - 5120) * 256 + t;
  if (i < 1536) {
    float4 m = ((const float4*)bmuh)[i];
    float4 r = ((const float4*)brhoh)[i];
    float4 e = ((const float4*)epsbh)[i];
    float4 o;
    o.x = m.x + e.x * sp(r.x);
    o.y = m.y + e.y * sp(r.y);
    o.z = m.z + e.z * sp(r.z);
    o.w = m.w + e.w * sp(r.w);
    ((float4*)bh)[i] = o;
    return;
  }
  i -= 1536;
  if (i < 512) {
    float4 m = ((const float4*)wmuo)[i];
    float4 r = ((const float4*)wrhoo)[i];
    float4 e = ((const float4*)epswo)[i];
    float4 o;
    o.x = m.x + e.x * sp(r.x);
    o.y = m.y + e.y * sp(r.y);
    o.z = m.z + e.z * sp(r.z);
    o.w = m.w + e.w * sp(r.w);
    ((float4*)wo)[i] = o;
    return;
  }
  i -= 512;
  if (i == 0) {
    bo[0] = bmuo[0] + epsbo[0] * sp(brhoo[0]);
  }
}

// ---------------- GEMM: C = relu(A @ W^T + bias), all bf16 in / bf16 out ----
// A: MxK row-major bf16 (M=4096), W: NxK row-major bf16 (N=2048), K=2048.
// 128x128 block tile, BK=64. R2 change: 512 threads = 8 waves (2x4 grid),
// wave tile 64x32 via 4x2 grid of 16x16x32 MFMA tiles -> 16 waves/CU at
// 2 blocks/CU (was 8 waves/CU). Same tiles, same global traffic.
// global_load_lds(16B) staging with XOR swizzle folded into the global addr.
// XCD-aware 1D remap: each XCD's 64 co-resident blocks cover an 8x8 patch.
__global__ __launch_bounds__(512) void gemm_relu_kernel(
    const unsigned short* __restrict__ A,
    const unsigned short* __restrict__ W,
    const float* __restrict__ bias,
    unsigned short* __restrict__ C,
    int N, int K)
{
  __shared__ unsigned short sA[128 * 64];
  __shared__ unsigned short sB[128 * 64];

  const int t = threadIdx.x;   // 0..511
  const int w = t >> 6;        // wave 0..7
  const int l = t & 63;
  const int lq = l >> 4;       // quad 0..3
  const int lr = l & 15;       // lane-in-quad 0..15

  // XCD-aware swizzle over 32 (M) x 16 (N) tiles
  const int id = blockIdx.x;
  const int p = id & 7;
  const int i4 = id >> 3;
  const int mt = (p & 3) * 8 + (i4 & 7);
  const int nt = (p >> 2) * 8 + (i4 >> 3);
  const int m0 = mt * 128;
  const int n0 = nt * 128;

  const int mw = (w >> 2) * 64;   // 0 / 64
  const int nw = (w & 3) * 32;    // 0 / 32 / 64 / 96

  f32x4 acc[4][2] = {};

  // staging geometry: 1024 chunks of 16B per matrix, 2 per thread
  int srow[2], sgc[2];
  #pragma unroll
  for (int i = 0; i < 2; ++i) {
    int c = i * 512 + t;
    srow[i] = c >> 3;                  // tile row 0..127
    sgc[i] = (c & 7) ^ (srow[i] & 7);  // swizzled global 16B-chunk col
  }

  for (int kt = 0; kt < K; kt += 64) {
    #pragma unroll
    for (int i = 0; i < 2; ++i) {
      int c = i * 512 + t;
      const unsigned short* ga = A + (size_t)(m0 + srow[i]) * K + kt + sgc[i] * 8;
      GLOAD_LDS16(ga, &sA[c * 8]);
      const unsigned short* gb = W + (size_t)(n0 + srow[i]) * K + kt + sgc[i] * 8;
      GLOAD_LDS16(gb, &sB[c * 8]);
    }
    __syncthreads();

    #pragma unroll
    for (int s = 0; s < 2; ++s) {
      bf16x8 af[4], bfr[2];
      int g = s * 4 + lq;
      #pragma unroll
      for (int i = 0; i < 4; ++i) {
        int ra = mw + i * 16 + lr;
        af[i] = *(const bf16x8*)&sA[ra * 64 + (g ^ (ra & 7)) * 8];
      }
      #pragma unroll
      for (int j = 0; j < 2; ++j) {
        int rb = nw + j * 16 + lr;
        bfr[j] = *(const bf16x8*)&sB[rb * 64 + (g ^ (rb & 7)) * 8];
      }
      #pragma unroll
      for (int i = 0; i < 4; ++i)
        #pragma unroll
        for (int j = 0; j < 2; ++j)
          acc[i][j] = __builtin_amdgcn_mfma_f32_16x16x32_bf16(af[i], bfr[j], acc[i][j], 0, 0, 0);
    }
    __syncthreads();
  }

  // epilogue: C[m][n], m = base + quad*4 + r, n = base + lr
  #pragma unroll
  for (int j = 0; j < 2; ++j) {
    int n = n0 + nw + j * 16 + lr;
    float bv = bias[n];
    #pragma unroll
    for (int i = 0; i < 4; ++i) {
      int mbase = m0 + mw + i * 16 + lq * 4;
      #pragma unroll
      for (int r = 0; r < 4; ++r) {
        float v = acc[i][j][r] + bv;
        v = fmaxf(v, 0.0f);
        C[(size_t)(mbase + r) * N + n] = f2bf(v);
      }
    }
  }
}

// ---------------- final: out[m] = h2[m,:] . wo + bo  (one wave per row) ----
__global__ void final_kernel(const unsigned short* __restrict__ H,
                             const float* __restrict__ wo,
                             const float* __restrict__ bo,
                             float* __restrict__ out)
{
  const int row = blockIdx.x * 4 + (threadIdx.x >> 6);
  const int l = threadIdx.x & 63;
  const unsigned short* hr = H + (size_t)row * DD;
  float sum = 0.0f;
  #pragma unroll
  for (int s = 0; s < 4; ++s) {
    int k = s * 512 + l * 8;
    uint4 hv = *(const uint4*)&hr[k];
    float4 w0 = *(const float4*)&wo[k];
    float4 w1 = *(const float4*)&wo[k + 4];
    sum += __uint_as_float(hv.x << 16) * w0.x;
    sum += __uint_as_float(hv.x & 0xffff0000u) * w0.y;
    sum += __uint_as_float(hv.y << 16) * w0.z;
    sum += __uint_as_float(hv.y & 0xffff0000u) * w0.w;
    sum += __uint_as_float(hv.z << 16) * w1.x;
    sum += __uint_as_float(hv.z & 0xffff0000u) * w1.y;
    sum += __uint_as_float(hv.w << 16) * w1.z;
    sum += __uint_as_float(hv.w & 0xffff0000u) * w1.w;
  }
  #pragma unroll
  for (int off = 32; off > 0; off >>= 1)
    sum += __shfl_down(sum, off, 64);
  if (l == 0) out[row] = sum + bo[0];
}

// ---------------- launch ----------------
extern "C" void kernel_launch(void* const* d_in, const int* in_sizes, int n_in,
                              void* d_out, int out_size, void* d_ws, size_t ws_size,
                              hipStream_t stream) {
  const float* x     = (const float*)d_in[0];
  const float* wmuh  = (const float*)d_in[1];
  const float* wrhoh = (const float*)d_in[2];
  const float* bmuh  = (const float*)d_in[3];
  const float* brhoh = (const float*)d_in[4];
  const float* wmuo  = (const float*)d_in[5];
  const float* wrhoo = (const float*)d_in[6];
  const float* bmuo  = (const float*)d_in[7];
  const float* brhoo = (const float*)d_in[8];
  const float* epswh = (const float*)d_in[9];
  const float* epsbh = (const float*)d_in[10];
  const float* epswo = (const float*)d_in[11];
  const float* epsbo = (const float*)d_in[12];

  char* ws = (char*)d_ws;
  unsigned short* Wh = (unsigned short*)(ws);                    // 25165824 B
  unsigned short* Xb = (unsigned short*)(ws + 25165824);         // 16777216 B
  unsigned short* Ha = (unsigned short*)(ws + 25165824 + 16777216);
  unsigned short* Hb = (unsigned short*)(ws + 25165824 + 2 * 16777216);
  float* bh = (float*)(ws + 25165824 + 3 * 16777216);            // 24576 B
  float* wo = (float*)(ws + 25165824 + 3 * 16777216 + 24576);    // 8192 B
  float* bo = (float*)(ws + 25165824 + 3 * 16777216 + 24576 + 8192);

  prep_kernel<<<5129, 256, 0, stream>>>(
      x, wmuh, wrhoh, bmuh, brhoh, wmuo, wrhoo, bmuo, brhoo,
      epswh, epsbh, epswo, epsbo, Wh, Xb, bh, wo, bo);

  const int ggrid = (BB / 128) * (DD / 128);  // 512 blocks, 1D with XCD swizzle
  gemm_relu_kernel<<<ggrid, 512, 0, stream>>>(Xb, Wh,               bh,          Ha, DD, DD);
  gemm_relu_kernel<<<ggrid, 512, 0, stream>>>(Ha, Wh + 1 * 4194304, bh + DD,     Hb, DD, DD);
  gemm_relu_kernel<<<ggrid, 512, 0, stream>>>(Hb, Wh + 2 * 4194304, bh + 2 * DD, Xb, DD, DD);

  final_kernel<<<BB / 4, 256, 0, stream>>>(Xb, wo, bo, (float*)d_out);
}

// Round 4
// 304.804 us; speedup vs baseline: 1.0830x; 1.0364x over previous
//
#include <hip/hip_runtime.h>

// ---------------- problem constants ----------------
// B=4096 batch, D=2048 dim, H=3 hidden layers, O=1 output
#define BB 4096
#define DD 2048

typedef float f32x4 __attribute__((ext_vector_type(4)));
typedef __bf16 bf16x8 __attribute__((ext_vector_type(8)));

typedef __attribute__((address_space(1))) unsigned int gl_u32;
typedef __attribute__((address_space(3))) unsigned int lds_u32;

#define GLOAD_LDS16(gptr, sptr) \
  __builtin_amdgcn_global_load_lds((gl_u32*)(void*)(gptr), (lds_u32*)(sptr), 16, 0, 0)

__device__ __forceinline__ unsigned short f2bf(float f) {
  unsigned int u = __float_as_uint(f);
  u += 0x7fffu + ((u >> 16) & 1u);   // round-to-nearest-even
  return (unsigned short)(u >> 16);
}

// fast softplus: v_exp_f32 + v_log_f32 (quarter-rate HW ops).
__device__ __forceinline__ float sp(float x) {
  float t = __expf(-fabsf(x));
  return fmaxf(x, 0.0f) + __logf(1.0f + t);
}

// materialize one vec4 of W: Wh[i] = bf16(mu[i] + eps[i]*softplus(rho[i]))
__device__ __forceinline__ void prep_w_vec4(
    const float* __restrict__ mu, const float* __restrict__ rho,
    const float* __restrict__ eps, unsigned short* __restrict__ Wh,
    long long i)
{
  float4 m = ((const float4*)mu)[i];
  float4 r = ((const float4*)rho)[i];
  float4 e = ((const float4*)eps)[i];
  ushort4 o;
  o.x = f2bf(m.x + e.x * sp(r.x));
  o.y = f2bf(m.y + e.y * sp(r.y));
  o.z = f2bf(m.z + e.z * sp(r.z));
  o.w = f2bf(m.w + e.w * sp(r.w));
  ((ushort4*)Wh)[i] = o;
}

__device__ __forceinline__ void prep_f32_vec4(
    const float* __restrict__ mu, const float* __restrict__ rho,
    const float* __restrict__ eps, float* __restrict__ out, long long i)
{
  float4 m = ((const float4*)mu)[i];
  float4 r = ((const float4*)rho)[i];
  float4 e = ((const float4*)eps)[i];
  float4 o;
  o.x = m.x + e.x * sp(r.x);
  o.y = m.y + e.y * sp(r.y);
  o.z = m.z + e.z * sp(r.z);
  o.w = m.w + e.w * sp(r.w);
  ((float4*)out)[i] = o;
}

// ---------------- prep0: only what gemm1 needs: W0->bf16, x->bf16, b0 ----
// 512 threads/block. Regions: [0,512) W0 | [512,1536) x | 1536 b0
__global__ __launch_bounds__(512) void prep0_kernel(
    const float* __restrict__ x,
    const float* __restrict__ wmuh, const float* __restrict__ wrhoh,
    const float* __restrict__ bmuh, const float* __restrict__ brhoh,
    const float* __restrict__ epswh, const float* __restrict__ epsbh,
    unsigned short* __restrict__ Wh, unsigned short* __restrict__ Xb,
    float* __restrict__ bh)
{
  const int b = blockIdx.x;
  const int t = threadIdx.x;
  if (b < 512) {
    long long base = (long long)b * 2048 + t;
    #pragma unroll
    for (int j = 0; j < 4; ++j)
      prep_w_vec4(wmuh, wrhoh, epswh, Wh, base + j * 512);
    return;
  }
  if (b < 1536) {
    long long base = (long long)(b - 512) * 2048 + t;
    #pragma unroll
    for (int j = 0; j < 4; ++j) {
      float4 v = ((const float4*)x)[base + j * 512];
      ushort4 o;
      o.x = f2bf(v.x); o.y = f2bf(v.y); o.z = f2bf(v.z); o.w = f2bf(v.w);
      ((ushort4*)Xb)[base + j * 512] = o;
    }
    return;
  }
  // b == 1536: bias layer 0 (512 vec4)
  prep_f32_vec4(bmuh, brhoh, epsbh, bh, t);
}

// ---------------- GEMM: C = relu(A @ W^T + bias), bf16 in / bf16 out ----
// A: MxK row-major bf16 (M=4096), W: NxK row-major bf16 (N=2048), K=2048.
// 128x128 block tile, BK=64, 512 threads = 8 waves (2x4), wave tile 64x32
// via 4x2 grid of 16x16x32 MFMA. global_load_lds(16B) staging with XOR
// swizzle folded into the global address. XCD-aware 1D remap: each XCD's 64
// co-resident gemm blocks cover an 8x8 tile patch (4MB B fits per-XCD L2).
// FUSION (R3): blocks [NGEMM, NGEMM+1025) materialize W1/W2/b1/b2/wo/bo —
// gemm1 has only 2 blocks/CU resident (16/32 wave slots); prep tail blocks
// backfill idle slots and overlap their ~117MB of traffic with gemm compute.
#define NGEMM 512

__global__ __launch_bounds__(512, 4) void gemm_relu_fused_kernel(
    const unsigned short* __restrict__ A,
    const unsigned short* __restrict__ W,
    const float* __restrict__ bias,
    unsigned short* __restrict__ C,
    int N, int K, int fuse_prep,
    const float* __restrict__ wmuh, const float* __restrict__ wrhoh,
    const float* __restrict__ bmuh, const float* __restrict__ brhoh,
    const float* __restrict__ wmuo, const float* __restrict__ wrhoo,
    const float* __restrict__ bmuo, const float* __restrict__ brhoo,
    const float* __restrict__ epswh, const float* __restrict__ epsbh,
    const float* __restrict__ epswo, const float* __restrict__ epsbo,
    unsigned short* __restrict__ Wh, float* __restrict__ bh,
    float* __restrict__ wo, float* __restrict__ bo)
{
  __shared__ unsigned short sA[128 * 64];
  __shared__ unsigned short sB[128 * 64];

  const int id = blockIdx.x;
  const int t = threadIdx.x;   // 0..511

  if (id >= NGEMM) {
    // ---- fused prep tail: W1, W2 (1024 blocks), smalls (1 block) ----
    const int pb = id - NGEMM;
    if (pb < 1024) {
      // layers 1..2: vec4 idx 1048576 .. 3145727
      long long base = 1048576LL + (long long)pb * 2048 + t;
      #pragma unroll
      for (int j = 0; j < 4; ++j)
        prep_w_vec4(wmuh, wrhoh, epswh, Wh, base + j * 512);
      return;
    }
    // smalls: b1,b2 (bh vec4 512..1535), wo (512 vec4), bo (1)
    #pragma unroll
    for (int j = 0; j < 2; ++j)
      prep_f32_vec4(bmuh, brhoh, epsbh, bh, 512 + j * 512 + t);
    prep_f32_vec4(wmuo, wrhoo, epswo, wo, t);
    if (t == 0) bo[0] = bmuo[0] + epsbo[0] * sp(brhoo[0]);
    return;
  }

  // ---- GEMM path ----
  const int w = t >> 6;        // wave 0..7
  const int l = t & 63;
  const int lq = l >> 4;       // quad 0..3
  const int lr = l & 15;       // lane-in-quad 0..15

  const int p = id & 7;
  const int i4 = id >> 3;
  const int mt = (p & 3) * 8 + (i4 & 7);
  const int nt = (p >> 2) * 8 + (i4 >> 3);
  const int m0 = mt * 128;
  const int n0 = nt * 128;

  const int mw = (w >> 2) * 64;   // 0 / 64
  const int nw = (w & 3) * 32;    // 0 / 32 / 64 / 96

  f32x4 acc[4][2] = {};

  int srow[2], sgc[2];
  #pragma unroll
  for (int i = 0; i < 2; ++i) {
    int c = i * 512 + t;
    srow[i] = c >> 3;                  // tile row 0..127
    sgc[i] = (c & 7) ^ (srow[i] & 7);  // swizzled global 16B-chunk col
  }

  for (int kt = 0; kt < K; kt += 64) {
    #pragma unroll
    for (int i = 0; i < 2; ++i) {
      int c = i * 512 + t;
      const unsigned short* ga = A + (size_t)(m0 + srow[i]) * K + kt + sgc[i] * 8;
      GLOAD_LDS16(ga, &sA[c * 8]);
      const unsigned short* gb = W + (size_t)(n0 + srow[i]) * K + kt + sgc[i] * 8;
      GLOAD_LDS16(gb, &sB[c * 8]);
    }
    __syncthreads();

    #pragma unroll
    for (int s = 0; s < 2; ++s) {
      bf16x8 af[4], bfr[2];
      int g = s * 4 + lq;
      #pragma unroll
      for (int i = 0; i < 4; ++i) {
        int ra = mw + i * 16 + lr;
        af[i] = *(const bf16x8*)&sA[ra * 64 + (g ^ (ra & 7)) * 8];
      }
      #pragma unroll
      for (int j = 0; j < 2; ++j) {
        int rb = nw + j * 16 + lr;
        bfr[j] = *(const bf16x8*)&sB[rb * 64 + (g ^ (rb & 7)) * 8];
      }
      #pragma unroll
      for (int i = 0; i < 4; ++i)
        #pragma unroll
        for (int j = 0; j < 2; ++j)
          acc[i][j] = __builtin_amdgcn_mfma_f32_16x16x32_bf16(af[i], bfr[j], acc[i][j], 0, 0, 0);
    }
    __syncthreads();
  }

  #pragma unroll
  for (int j = 0; j < 2; ++j) {
    int n = n0 + nw + j * 16 + lr;
    float bv = bias[n];
    #pragma unroll
    for (int i = 0; i < 4; ++i) {
      int mbase = m0 + mw + i * 16 + lq * 4;
      #pragma unroll
      for (int r = 0; r < 4; ++r) {
        float v = acc[i][j][r] + bv;
        v = fmaxf(v, 0.0f);
        C[(size_t)(mbase + r) * N + n] = f2bf(v);
      }
    }
  }
}

// plain gemm (layers 2,3): same as above without the prep tail
__global__ __launch_bounds__(512, 4) void gemm_relu_kernel(
    const unsigned short* __restrict__ A,
    const unsigned short* __restrict__ W,
    const float* __restrict__ bias,
    unsigned short* __restrict__ C,
    int N, int K)
{
  __shared__ unsigned short sA[128 * 64];
  __shared__ unsigned short sB[128 * 64];

  const int t = threadIdx.x;
  const int w = t >> 6;
  const int l = t & 63;
  const int lq = l >> 4;
  const int lr = l & 15;

  const int id = blockIdx.x;
  const int p = id & 7;
  const int i4 = id >> 3;
  const int mt = (p & 3) * 8 + (i4 & 7);
  const int nt = (p >> 2) * 8 + (i4 >> 3);
  const int m0 = mt * 128;
  const int n0 = nt * 128;

  const int mw = (w >> 2) * 64;
  const int nw = (w & 3) * 32;

  f32x4 acc[4][2] = {};

  int srow[2], sgc[2];
  #pragma unroll
  for (int i = 0; i < 2; ++i) {
    int c = i * 512 + t;
    srow[i] = c >> 3;
    sgc[i] = (c & 7) ^ (srow[i] & 7);
  }

  for (int kt = 0; kt < K; kt += 64) {
    #pragma unroll
    for (int i = 0; i < 2; ++i) {
      int c = i * 512 + t;
      const unsigned short* ga = A + (size_t)(m0 + srow[i]) * K + kt + sgc[i] * 8;
      GLOAD_LDS16(ga, &sA[c * 8]);
      const unsigned short* gb = W + (size_t)(n0 + srow[i]) * K + kt + sgc[i] * 8;
      GLOAD_LDS16(gb, &sB[c * 8]);
    }
    __syncthreads();

    #pragma unroll
    for (int s = 0; s < 2; ++s) {
      bf16x8 af[4], bfr[2];
      int g = s * 4 + lq;
      #pragma unroll
      for (int i = 0; i < 4; ++i) {
        int ra = mw + i * 16 + lr;
        af[i] = *(const bf16x8*)&sA[ra * 64 + (g ^ (ra & 7)) * 8];
      }
      #pragma unroll
      for (int j = 0; j < 2; ++j) {
        int rb = nw + j * 16 + lr;
        bfr[j] = *(const bf16x8*)&sB[rb * 64 + (g ^ (rb & 7)) * 8];
      }
      #pragma unroll
      for (int i = 0; i < 4; ++i)
        #pragma unroll
        for (int j = 0; j < 2; ++j)
          acc[i][j] = __builtin_amdgcn_mfma_f32_16x16x32_bf16(af[i], bfr[j], acc[i][j], 0, 0, 0);
    }
    __syncthreads();
  }

  #pragma unroll
  for (int j = 0; j < 2; ++j) {
    int n = n0 + nw + j * 16 + lr;
    float bv = bias[n];
    #pragma unroll
    for (int i = 0; i < 4; ++i) {
      int mbase = m0 + mw + i * 16 + lq * 4;
      #pragma unroll
      for (int r = 0; r < 4; ++r) {
        float v = acc[i][j][r] + bv;
        v = fmaxf(v, 0.0f);
        C[(size_t)(mbase + r) * N + n] = f2bf(v);
      }
    }
  }
}

// ---------------- final: out[m] = h2[m,:] . wo + bo  (one wave per row) ----
__global__ void final_kernel(const unsigned short* __restrict__ H,
                             const float* __restrict__ wo,
                             const float* __restrict__ bo,
                             float* __restrict__ out)
{
  const int row = blockIdx.x * 4 + (threadIdx.x >> 6);
  const int l = threadIdx.x & 63;
  const unsigned short* hr = H + (size_t)row * DD;
  float sum = 0.0f;
  #pragma unroll
  for (int s = 0; s < 4; ++s) {
    int k = s * 512 + l * 8;
    uint4 hv = *(const uint4*)&hr[k];
    float4 w0 = *(const float4*)&wo[k];
    float4 w1 = *(const float4*)&wo[k + 4];
    sum += __uint_as_float(hv.x << 16) * w0.x;
    sum += __uint_as_float(hv.x & 0xffff0000u) * w0.y;
    sum += __uint_as_float(hv.y << 16) * w0.z;
    sum += __uint_as_float(hv.y & 0xffff0000u) * w0.w;
    sum += __uint_as_float(hv.z << 16) * w1.x;
    sum += __uint_as_float(hv.z & 0xffff0000u) * w1.y;
    sum += __uint_as_float(hv.w << 16) * w1.z;
    sum += __uint_as_float(hv.w & 0xffff0000u) * w1.w;
  }
  #pragma unroll
  for (int off = 32; off > 0; off >>= 1)
    sum += __shfl_down(sum, off, 64);
  if (l == 0) out[row] = sum + bo[0];
}

// ---------------- launch ----------------
extern "C" void kernel_launch(void* const* d_in, const int* in_sizes, int n_in,
                              void* d_out, int out_size, void* d_ws, size_t ws_size,
                              hipStream_t stream) {
  const float* x     = (const float*)d_in[0];
  const float* wmuh  = (const float*)d_in[1];
  const float* wrhoh = (const float*)d_in[2];
  const float* bmuh  = (const float*)d_in[3];
  const float* brhoh = (const float*)d_in[4];
  const float* wmuo  = (const float*)d_in[5];
  const float* wrhoo = (const float*)d_in[6];
  const float* bmuo  = (const float*)d_in[7];
  const float* brhoo = (const float*)d_in[8];
  const float* epswh = (const float*)d_in[9];
  const float* epsbh = (const float*)d_in[10];
  const float* epswo = (const float*)d_in[11];
  const float* epsbo = (const float*)d_in[12];

  char* ws = (char*)d_ws;
  unsigned short* Wh = (unsigned short*)(ws);                    // 25165824 B
  unsigned short* Xb = (unsigned short*)(ws + 25165824);         // 16777216 B
  unsigned short* Ha = (unsigned short*)(ws + 25165824 + 16777216);
  unsigned short* Hb = (unsigned short*)(ws + 25165824 + 2 * 16777216);
  float* bh = (float*)(ws + 25165824 + 3 * 16777216);            // 24576 B
  float* wo = (float*)(ws + 25165824 + 3 * 16777216 + 24576);    // 8192 B
  float* bo = (float*)(ws + 25165824 + 3 * 16777216 + 24576 + 8192);

  // prep0: W0 (512 blocks) + x (1024 blocks) + b0 (1 block)
  prep0_kernel<<<1537, 512, 0, stream>>>(
      x, wmuh, wrhoh, bmuh, brhoh, epswh, epsbh, Wh, Xb, bh);

  // gemm1 + fused prep of W1/W2/b1/b2/wo/bo (1025 tail blocks)
  gemm_relu_fused_kernel<<<NGEMM + 1025, 512, 0, stream>>>(
      Xb, Wh, bh, Ha, DD, DD, 1,
      wmuh, wrhoh, bmuh, brhoh, wmuo, wrhoo, bmuo, brhoo,
      epswh, epsbh, epswo, epsbo, Wh, bh, wo, bo);

  gemm_relu_kernel<<<NGEMM, 512, 0, stream>>>(Ha, Wh + 1 * 4194304, bh + DD,     Hb, DD, DD);
  gemm_relu_kernel<<<NGEMM, 512, 0, stream>>>(Hb, Wh + 2 * 4194304, bh + 2 * DD, Xb, DD, DD);

  final_kernel<<<BB / 4, 256, 0, stream>>>(Xb, wo, bo, (float*)d_out);
}

// Round 6
// 298.269 us; speedup vs baseline: 1.1067x; 1.0219x over previous
//
#include <hip/hip_runtime.h>

// ---------------- problem constants ----------------
// B=4096 batch, D=2048 dim, H=3 hidden layers, O=1 output
#define BB 4096
#define DD 2048

typedef float f32x4 __attribute__((ext_vector_type(4)));
typedef __bf16 bf16x8 __attribute__((ext_vector_type(8)));

typedef __attribute__((address_space(1))) unsigned int gl_u32;
typedef __attribute__((address_space(3))) unsigned int lds_u32;

#define GLOAD_LDS16(gptr, sptr) \
  __builtin_amdgcn_global_load_lds((gl_u32*)(void*)(gptr), (lds_u32*)(sptr), 16, 0, 0)

__device__ __forceinline__ unsigned short f2bf(float f) {
  unsigned int u = __float_as_uint(f);
  u += 0x7fffu + ((u >> 16) & 1u);   // round-to-nearest-even
  return (unsigned short)(u >> 16);
}

// fast softplus: v_exp_f32 + v_log_f32 (quarter-rate HW ops).
__device__ __forceinline__ float sp(float x) {
  float t = __expf(-fabsf(x));
  return fmaxf(x, 0.0f) + __logf(1.0f + t);
}

__device__ __forceinline__ void prep_w_vec4(
    const float* __restrict__ mu, const float* __restrict__ rho,
    const float* __restrict__ eps, unsigned short* __restrict__ Wh,
    long long i)
{
  float4 m = ((const float4*)mu)[i];
  float4 r = ((const float4*)rho)[i];
  float4 e = ((const float4*)eps)[i];
  ushort4 o;
  o.x = f2bf(m.x + e.x * sp(r.x));
  o.y = f2bf(m.y + e.y * sp(r.y));
  o.z = f2bf(m.z + e.z * sp(r.z));
  o.w = f2bf(m.w + e.w * sp(r.w));
  ((ushort4*)Wh)[i] = o;
}

__device__ __forceinline__ void prep_f32_vec4(
    const float* __restrict__ mu, const float* __restrict__ rho,
    const float* __restrict__ eps, float* __restrict__ out, long long i)
{
  float4 m = ((const float4*)mu)[i];
  float4 r = ((const float4*)rho)[i];
  float4 e = ((const float4*)eps)[i];
  float4 o;
  o.x = m.x + e.x * sp(r.x);
  o.y = m.y + e.y * sp(r.y);
  o.z = m.z + e.z * sp(r.z);
  o.w = m.w + e.w * sp(r.w);
  ((float4*)out)[i] = o;
}

// ---------------- prep0: only what gemm1 needs: W0->bf16, x->bf16, b0 ----
// 512 threads/block. Regions: [0,512) W0 | [512,1536) x | 1536 b0
__global__ __launch_bounds__(512) void prep0_kernel(
    const float* __restrict__ x,
    const float* __restrict__ wmuh, const float* __restrict__ wrhoh,
    const float* __restrict__ bmuh, const float* __restrict__ brhoh,
    const float* __restrict__ epswh, const float* __restrict__ epsbh,
    unsigned short* __restrict__ Wh, unsigned short* __restrict__ Xb,
    float* __restrict__ bh)
{
  const int b = blockIdx.x;
  const int t = threadIdx.x;
  if (b < 512) {
    long long base = (long long)b * 2048 + t;
    #pragma unroll
    for (int j = 0; j < 4; ++j)
      prep_w_vec4(wmuh, wrhoh, epswh, Wh, base + j * 512);
    return;
  }
  if (b < 1536) {
    long long base = (long long)(b - 512) * 2048 + t;
    #pragma unroll
    for (int j = 0; j < 4; ++j) {
      float4 v = ((const float4*)x)[base + j * 512];
      ushort4 o;
      o.x = f2bf(v.x); o.y = f2bf(v.y); o.z = f2bf(v.z); o.w = f2bf(v.w);
      ((ushort4*)Xb)[base + j * 512] = o;
    }
    return;
  }
  // b == 1536: bias layer 0 (512 vec4)
  prep_f32_vec4(bmuh, brhoh, epsbh, bh, t);
}

// ---------------- GEMM geometry: R3's passing config ----------------
// C = relu(A @ W^T + bias). A: 4096x2048 bf16 row-major, W: 2048x2048 bf16.
// 128x128 tile, BK=64, 512 threads = 8 waves (2x4), wave tile 64x32 via 4x2
// grid of 16x16x32 MFMA. global_load_lds(16B) with XOR swizzle folded into
// the global address. XCD-aware remap: patch p=id&7 -> 8x8 tile patch.
// d_out rule (R5): OVERWRITE ONLY, single producer kernel — no cross-dispatch
// RMW on d_out (R4's prep-init + atomicAdd diverged after graph replays).
#define NGEMM 512

struct GemmCoords { int m0, n0, mw, nw; int srow[2], sgc[2]; };

__device__ __forceinline__ GemmCoords gemm_coords(int id, int t) {
  GemmCoords g;
  const int w = t >> 6;
  const int p = id & 7;
  const int i4 = id >> 3;
  const int mt = (p & 3) * 8 + (i4 & 7);    // 0..31
  const int nt = (p >> 2) * 8 + (i4 >> 3);  // 0..15
  g.m0 = mt * 128;
  g.n0 = nt * 128;
  g.mw = (w >> 2) * 64;
  g.nw = (w & 3) * 32;
  #pragma unroll
  for (int i = 0; i < 2; ++i) {
    int c = i * 512 + t;
    g.srow[i] = c >> 3;                // tile row 0..127
    g.sgc[i] = (c & 7) ^ (g.srow[i] & 7);
  }
  return g;
}

__device__ __forceinline__ void gemm_mainloop(
    const unsigned short* __restrict__ A,
    const unsigned short* __restrict__ W,
    unsigned short* sA, unsigned short* sB,
    const GemmCoords& gc, int t, f32x4 (&acc)[4][2])
{
  const int K = DD;
  const int l = t & 63;
  const int lq = l >> 4;
  const int lr = l & 15;
  for (int kt = 0; kt < K; kt += 64) {
    #pragma unroll
    for (int i = 0; i < 2; ++i) {
      int c = i * 512 + t;
      const unsigned short* ga = A + (size_t)(gc.m0 + gc.srow[i]) * K + kt + gc.sgc[i] * 8;
      GLOAD_LDS16(ga, &sA[c * 8]);
      const unsigned short* gb = W + (size_t)(gc.n0 + gc.srow[i]) * K + kt + gc.sgc[i] * 8;
      GLOAD_LDS16(gb, &sB[c * 8]);
    }
    __syncthreads();

    #pragma unroll
    for (int s = 0; s < 2; ++s) {
      bf16x8 af[4], bfr[2];
      int g = s * 4 + lq;
      #pragma unroll
      for (int i = 0; i < 4; ++i) {
        int ra = gc.mw + i * 16 + lr;
        af[i] = *(const bf16x8*)&sA[ra * 64 + (g ^ (ra & 7)) * 8];
      }
      #pragma unroll
      for (int j = 0; j < 2; ++j) {
        int rb = gc.nw + j * 16 + lr;
        bfr[j] = *(const bf16x8*)&sB[rb * 64 + (g ^ (rb & 7)) * 8];
      }
      #pragma unroll
      for (int i = 0; i < 4; ++i)
        #pragma unroll
        for (int j = 0; j < 2; ++j)
          acc[i][j] = __builtin_amdgcn_mfma_f32_16x16x32_bf16(af[i], bfr[j], acc[i][j], 0, 0, 0);
    }
    __syncthreads();
  }
}

__device__ __forceinline__ void gemm_epilogue_store(
    const GemmCoords& gc, int t, f32x4 (&acc)[4][2],
    const float* __restrict__ bias, unsigned short* __restrict__ C)
{
  const int N = DD;
  const int l = t & 63;
  const int lq = l >> 4;
  const int lr = l & 15;
  #pragma unroll
  for (int j = 0; j < 2; ++j) {
    int n = gc.n0 + gc.nw + j * 16 + lr;
    float bv = bias[n];
    #pragma unroll
    for (int i = 0; i < 4; ++i) {
      int mbase = gc.m0 + gc.mw + i * 16 + lq * 4;
      #pragma unroll
      for (int r = 0; r < 4; ++r) {
        float v = fmaxf(acc[i][j][r] + bv, 0.0f);
        C[(size_t)(mbase + r) * N + n] = f2bf(v);
      }
    }
  }
}

// gemm1 + fused prep tail (W1/W2/b1/b2/wo)
__global__ __launch_bounds__(512, 4) void gemm_relu_fused_kernel(
    const unsigned short* __restrict__ A,
    const unsigned short* __restrict__ W,
    const float* __restrict__ bias,
    unsigned short* __restrict__ C,
    const float* __restrict__ wmuh, const float* __restrict__ wrhoh,
    const float* __restrict__ bmuh, const float* __restrict__ brhoh,
    const float* __restrict__ wmuo, const float* __restrict__ wrhoo,
    const float* __restrict__ epswh, const float* __restrict__ epsbh,
    const float* __restrict__ epswo,
    unsigned short* __restrict__ Wh, float* __restrict__ bh,
    float* __restrict__ wo)
{
  __shared__ unsigned short sA[128 * 64];
  __shared__ unsigned short sB[128 * 64];

  const int id = blockIdx.x;
  const int t = threadIdx.x;   // 0..511

  if (id >= NGEMM) {
    const int pb = id - NGEMM;
    if (pb < 1024) {
      // W1,W2: vec4 idx 1048576..3145727, 2048/block, 4/thread
      long long base = 1048576LL + (long long)pb * 2048 + t;
      #pragma unroll
      for (int j = 0; j < 4; ++j)
        prep_w_vec4(wmuh, wrhoh, epswh, Wh, base + j * 512);
      return;
    }
    // smalls: b1,b2 (bh vec4 512..1535), wo (512 vec4, t<512 exactly covers)
    #pragma unroll
    for (int j = 0; j < 2; ++j)
      prep_f32_vec4(bmuh, brhoh, epsbh, bh, 512 + j * 512 + t);
    prep_f32_vec4(wmuo, wrhoo, epswo, wo, t);
    return;
  }

  GemmCoords gc = gemm_coords(id, t);
  f32x4 acc[4][2] = {};
  gemm_mainloop(A, W, sA, sB, gc, t, acc);
  gemm_epilogue_store(gc, t, acc, bias, C);
}

// plain gemm (layer 2)
__global__ __launch_bounds__(512, 4) void gemm_relu_kernel(
    const unsigned short* __restrict__ A,
    const unsigned short* __restrict__ W,
    const float* __restrict__ bias,
    unsigned short* __restrict__ C)
{
  __shared__ unsigned short sA[128 * 64];
  __shared__ unsigned short sB[128 * 64];
  const int t = threadIdx.x;
  GemmCoords gc = gemm_coords(blockIdx.x, t);
  f32x4 acc[4][2] = {};
  gemm_mainloop(A, W, sA, sB, gc, t, acc);
  gemm_epilogue_store(gc, t, acc, bias, C);
}

// layer 3 + dot with wo, NO atomics / NO d_out access:
// Pbuf[nt*4096 + m] = sum_{n in this block's 128 cols} relu(acc+b2[n])*wo[n]
__global__ __launch_bounds__(512, 4) void gemm_relu_dot_kernel(
    const unsigned short* __restrict__ A,
    const unsigned short* __restrict__ W,
    const float* __restrict__ bias,
    const float* __restrict__ wo,
    float* __restrict__ Pbuf)
{
  __shared__ unsigned short sA[128 * 64];
  __shared__ unsigned short sB[128 * 64];
  const int t = threadIdx.x;

  GemmCoords gc = gemm_coords(blockIdx.x, t);
  f32x4 acc[4][2] = {};
  gemm_mainloop(A, W, sA, sB, gc, t, acc);

  const int l = t & 63;
  const int w = t >> 6;
  const int lq = l >> 4;
  const int lr = l & 15;
  const int nq = w & 3;   // which 32-col quarter this wave handles

  float bv[2], wv[2];
  #pragma unroll
  for (int j = 0; j < 2; ++j) {
    int n = gc.n0 + gc.nw + j * 16 + lr;
    bv[j] = bias[n];
    wv[j] = wo[n];
  }
  float partial[4][4];
  #pragma unroll
  for (int i = 0; i < 4; ++i)
    #pragma unroll
    for (int r = 0; r < 4; ++r)
      partial[i][r] = fmaxf(acc[i][0][r] + bv[0], 0.0f) * wv[0]
                    + fmaxf(acc[i][1][r] + bv[1], 0.0f) * wv[1];

  // butterfly over lr (lane bits 0..3)
  #pragma unroll
  for (int d = 1; d <= 8; d <<= 1)
    #pragma unroll
    for (int i = 0; i < 4; ++i)
      #pragma unroll
      for (int r = 0; r < 4; ++r)
        partial[i][r] += __shfl_xor(partial[i][r], d, 64);

  // cross-wave reduce via LDS (reuse sA; mainloop ended with __syncthreads)
  float* sRed = (float*)sA;   // [128 rows][4 quarters]
  if (lr == 0) {
    #pragma unroll
    for (int i = 0; i < 4; ++i)
      #pragma unroll
      for (int r = 0; r < 4; ++r) {
        int row = gc.mw + i * 16 + lq * 4 + r;   // 0..127 in tile
        sRed[row * 4 + nq] = partial[i][r];
      }
  }
  __syncthreads();
  if (t < 128) {
    float s = sRed[t * 4 + 0] + sRed[t * 4 + 1] + sRed[t * 4 + 2] + sRed[t * 4 + 3];
    int nt = gc.n0 >> 7;
    Pbuf[nt * BB + gc.m0 + t] = s;
  }
}

// final reduce: out[m] = bo + sum_{nt<16} Pbuf[nt*4096+m]  (overwrite-only)
__global__ __launch_bounds__(256) void reduce_out_kernel(
    const float* __restrict__ Pbuf,
    const float* __restrict__ bmuo, const float* __restrict__ brhoo,
    const float* __restrict__ epsbo,
    float* __restrict__ out)
{
  const int m = blockIdx.x * 256 + threadIdx.x;
  float s = bmuo[0] + epsbo[0] * sp(brhoo[0]);
  #pragma unroll
  for (int nt = 0; nt < 16; ++nt)
    s += Pbuf[nt * BB + m];
  out[m] = s;
}

// ---------------- launch ----------------
extern "C" void kernel_launch(void* const* d_in, const int* in_sizes, int n_in,
                              void* d_out, int out_size, void* d_ws, size_t ws_size,
                              hipStream_t stream) {
  const float* x     = (const float*)d_in[0];
  const float* wmuh  = (const float*)d_in[1];
  const float* wrhoh = (const float*)d_in[2];
  const float* bmuh  = (const float*)d_in[3];
  const float* brhoh = (const float*)d_in[4];
  const float* wmuo  = (const float*)d_in[5];
  const float* wrhoo = (const float*)d_in[6];
  const float* bmuo  = (const float*)d_in[7];
  const float* brhoo = (const float*)d_in[8];
  const float* epswh = (const float*)d_in[9];
  const float* epsbh = (const float*)d_in[10];
  const float* epswo = (const float*)d_in[11];
  const float* epsbo = (const float*)d_in[12];

  char* ws = (char*)d_ws;
  unsigned short* Wh = (unsigned short*)(ws);                       // 25165824 B
  unsigned short* Xb = (unsigned short*)(ws + 25165824);            // 16777216 B
  unsigned short* Ha = (unsigned short*)(ws + 25165824 + 16777216);
  unsigned short* Hb = (unsigned short*)(ws + 25165824 + 2 * 16777216);
  float* bh   = (float*)(ws + 25165824 + 3 * 16777216);             // 24576 B
  float* wo   = (float*)(ws + 25165824 + 3 * 16777216 + 24576);     // 8192 B
  float* Pbuf = (float*)(ws + 25165824 + 3 * 16777216 + 24576 + 8192); // 262144 B

  prep0_kernel<<<1537, 512, 0, stream>>>(
      x, wmuh, wrhoh, bmuh, brhoh, epswh, epsbh, Wh, Xb, bh);

  gemm_relu_fused_kernel<<<NGEMM + 1025, 512, 0, stream>>>(
      Xb, Wh, bh, Ha,
      wmuh, wrhoh, bmuh, brhoh, wmuo, wrhoo,
      epswh, epsbh, epswo, Wh, bh, wo);

  gemm_relu_kernel<<<NGEMM, 512, 0, stream>>>(Ha, Wh + 1 * 4194304, bh + DD, Hb);

  gemm_relu_dot_kernel<<<NGEMM, 512, 0, stream>>>(
      Hb, Wh + 2 * 4194304, bh + 2 * DD, wo, Pbuf);

  reduce_out_kernel<<<BB / 256, 256, 0, stream>>>(
      Pbuf, bmuo, brhoo, epsbo, (float*)d_out);
}